// Round 1
// baseline (409.034 us; speedup 1.0000x reference)
//
#include <hip/hip_runtime.h>

#define N_NODES 100000
#define IN_F 256
#define OUT_F 128
#define RPB 64                                   // rows per bucket
#define RSHIFT 6
#define NB 1563                                  // ceil(N_NODES/RPB)
#define CAPG 2560                                // fixed per-bucket ebuf capacity
#define CHUNK_SC 8192                            // edges per scatter block

typedef short bf16x8 __attribute__((ext_vector_type(8)));
typedef float f32x4  __attribute__((ext_vector_type(4)));

static __device__ __forceinline__ unsigned short f2bf(float f) {
    unsigned int u = __float_as_uint(f);
    u = (u + 0x7FFF + ((u >> 16) & 1)) >> 16;    // round-to-nearest-even
    return (unsigned short)u;
}

// ---------------- w transpose + bf16 cast + gcur init ----------------------
__global__ __launch_bounds__(256) void wt_kernel(const float* __restrict__ w,
                                                 unsigned short* __restrict__ wT,
                                                 int* __restrict__ gcur) {
    int n = blockIdx.x;                          // 0..127
    int k = threadIdx.x;                         // 0..255
    wT[n * IN_F + k] = f2bf(w[(size_t)k * OUT_F + n]);
    if (blockIdx.x < 7) {
        int i = blockIdx.x * 256 + threadIdx.x;
        if (i < NB) gcur[i] = i * CAPG;
    }
}

// ---------------- MFMA GEMM: 32-row tiles, 3125 blocks ----------------------
// Block 256 threads (4 waves). Wave w: row-tile (w&1), col-tiles (w>>1)*4..+4.
__global__ __launch_bounds__(256) void gemm_mfma_kernel(const float* __restrict__ x,
                                                        const unsigned short* __restrict__ wT,
                                                        unsigned short* __restrict__ supb) {
    __shared__ unsigned short A_lds[32][72];     // [row][k] bf16
    __shared__ unsigned short B_lds[128][72];    // [n][k]   bf16

    const int tid  = threadIdx.x;
    const int wave = tid >> 6;
    const int lane = tid & 63;
    const int quad = lane >> 4;
    const int l15  = lane & 15;
    const int rt   = wave & 1;                   // row-tile
    const int cg   = (wave >> 1) * 4;            // col-tile base
    const int row_base = blockIdx.x * 32;        // 100000/32 = 3125 exact

    f32x4 acc[4];
#pragma unroll
    for (int c = 0; c < 4; ++c) acc[c] = (f32x4){0.f, 0.f, 0.f, 0.f};

    const int s_row = tid >> 3;                  // 0..31
    const int s_kc  = (tid & 7) * 8;             // 0..56
    const float* xrow = x + (size_t)(row_base + s_row) * IN_F + s_kc;

    const int b_n  = tid >> 1;                   // 0..127
    const int b_kc = (tid & 1) * 32;             // 0 or 32
    const unsigned short* wrow = wT + (size_t)b_n * IN_F + b_kc;

    for (int k0 = 0; k0 < IN_F; k0 += 64) {
        __syncthreads();

        float4 xa = *(const float4*)(xrow + k0);
        float4 xb = *(const float4*)(xrow + k0 + 4);
        ushort4 ua = {f2bf(xa.x), f2bf(xa.y), f2bf(xa.z), f2bf(xa.w)};
        ushort4 ub = {f2bf(xb.x), f2bf(xb.y), f2bf(xb.z), f2bf(xb.w)};
        *(ushort4*)&A_lds[s_row][s_kc]     = ua;
        *(ushort4*)&A_lds[s_row][s_kc + 4] = ub;

#pragma unroll
        for (int j = 0; j < 4; ++j) {
            float4 wv = *(const float4*)(wrow + k0 + j * 8);
            *(float4*)&B_lds[b_n][b_kc + j * 8] = wv;
        }

        __syncthreads();

#pragma unroll
        for (int ks = 0; ks < 64; ks += 32) {
            bf16x8 af = *(const bf16x8*)&A_lds[rt * 16 + l15][ks + quad * 8];
#pragma unroll
            for (int c = 0; c < 4; ++c) {
                bf16x8 bfr = *(const bf16x8*)&B_lds[(cg + c) * 16 + l15][ks + quad * 8];
                acc[c] = __builtin_amdgcn_mfma_f32_16x16x32_bf16(af, bfr, acc[c], 0, 0, 0);
            }
        }
    }

    // C/D layout: col = lane&15, row = quad*4 + reg
#pragma unroll
    for (int c = 0; c < 4; ++c) {
#pragma unroll
        for (int r = 0; r < 4; ++r) {
            int orow = row_base + rt * 16 + quad * 4 + r;
            supb[(size_t)orow * OUT_F + (cg + c) * 16 + l15] = f2bf(acc[c][r]);
        }
    }
}

// ---------------- scatter: LDS hist + global range reservation --------------
__global__ __launch_bounds__(256) void scatter_kernel(const int* __restrict__ adj_row,
                                                      const int* __restrict__ adj_col,
                                                      const float* __restrict__ adj_val,
                                                      int* __restrict__ gcur,
                                                      int2* __restrict__ ebuf, int E) {
    __shared__ int lh[NB];                       // 6.25 KB: count -> cursor
    const int tid = threadIdx.x;
    for (int b = tid; b < NB; b += 256) lh[b] = 0;
    const int base = blockIdx.x * CHUNK_SC;
    const int m = min(CHUNK_SC, E - base);
    __syncthreads();

    // pass 1: histogram (adj_row stays hot in L2 for pass 2)
#pragma unroll
    for (int j = 0; j < CHUNK_SC / 256; ++j) {
        int i = j * 256 + tid;
        if (i < m) atomicAdd(&lh[adj_row[base + i] >> RSHIFT], 1);
    }
    __syncthreads();

    // reserve contiguous runs in each bucket region
    for (int b = tid; b < NB; b += 256) {
        int c = lh[b];
        if (c) lh[b] = atomicAdd(&gcur[b], c);
    }
    __syncthreads();

    // pass 2: scatter
#pragma unroll
    for (int j = 0; j < CHUNK_SC / 256; ++j) {
        int i = j * 256 + tid;
        if (i < m) {
            int r  = adj_row[base + i];
            int bk = r >> RSHIFT;
            int pos = atomicAdd(&lh[bk], 1);
            if (pos < (bk + 1) * CAPG) {         // overflow guard
                int2 rec;
                rec.x = adj_col[base + i] | ((r & (RPB - 1)) << 17);
                rec.y = __float_as_int(adj_val[base + i]);
                ebuf[pos] = rec;
            }
        }
    }
}

// ---------------- SpMM: LDS counting-sort + dual-edge wide gather -----------
// Wave split into two 32-lane halves; each lane covers 4 features (dwordx2),
// half h processes edges k+2u+h. 2 edges per wave-load, 8 edges in flight.
__global__ __launch_bounds__(512) void spmm_kernel(const int2* __restrict__ ebuf,
                                                   const int* __restrict__ gcur,
                                                   const unsigned short* __restrict__ supb,
                                                   const float* __restrict__ bias,
                                                   float* __restrict__ out) {
    __shared__ int2 se[CAPG];                    // 20 KB sorted edges
    __shared__ int cnt[RPB];
    __shared__ int off[RPB];
    __shared__ int cur[RPB];

    const int tid  = threadIdx.x;
    const int b    = blockIdx.x;
    const int wave = tid >> 6;
    const int lane = tid & 63;
    const int h    = lane >> 5;                  // half 0/1
    const int l5   = lane & 31;                  // lane within half
    const int fe   = l5 << 2;                    // first feature (4 per lane)

    const int start = b * CAPG;
    int m = gcur[b] - start;
    if (m > CAPG) m = CAPG;

    if (tid < RPB) cnt[tid] = 0;
    __syncthreads();

    int2 ev[5];
#pragma unroll
    for (int j = 0; j < 5; ++j) {
        int i = j * 512 + tid;
        if (i < m) {
            ev[j] = ebuf[start + i];
            atomicAdd(&cnt[ev[j].x >> 17], 1);
        }
    }
    __syncthreads();

    if (tid < RPB) {
        int v = cnt[tid];
        int s = v;
#pragma unroll
        for (int d = 1; d < RPB; d <<= 1) {
            int t = __shfl_up(s, d, 64);
            if (tid >= d) s += t;
        }
        off[tid] = s - v;
        cur[tid] = s - v;
    }
    __syncthreads();

#pragma unroll
    for (int j = 0; j < 5; ++j) {
        int i = j * 512 + tid;
        if (i < m) {
            int p = atomicAdd(&cur[ev[j].x >> 17], 1);
            se[p] = ev[j];
        }
    }
    __syncthreads();

    float acc[8][4];
#pragma unroll
    for (int j = 0; j < 8; ++j)
#pragma unroll
        for (int q = 0; q < 4; ++q) acc[j][q] = 0.f;

#pragma unroll
    for (int j = 0; j < 8; ++j) {
        const int r = wave * 8 + j;
        const int o = off[r];
        const int c = cnt[r];
        int k = 0;
        // main: 8 edges per wave-iteration (4 per half), 4 dwordx2 loads in flight
        for (; k + 8 <= c; k += 8) {
            int2 e0 = se[o + k + h];
            int2 e1 = se[o + k + 2 + h];
            int2 e2 = se[o + k + 4 + h];
            int2 e3 = se[o + k + 6 + h];
            uint2 u0 = *(const uint2*)(supb + ((e0.x & 0x1FFFF) << 7) + fe);
            uint2 u1 = *(const uint2*)(supb + ((e1.x & 0x1FFFF) << 7) + fe);
            uint2 u2 = *(const uint2*)(supb + ((e2.x & 0x1FFFF) << 7) + fe);
            uint2 u3 = *(const uint2*)(supb + ((e3.x & 0x1FFFF) << 7) + fe);
            float v0 = __int_as_float(e0.y), v1 = __int_as_float(e1.y);
            float v2 = __int_as_float(e2.y), v3 = __int_as_float(e3.y);
            acc[j][0] = fmaf(v0, __uint_as_float(u0.x << 16),         acc[j][0]);
            acc[j][1] = fmaf(v0, __uint_as_float(u0.x & 0xFFFF0000u), acc[j][1]);
            acc[j][2] = fmaf(v0, __uint_as_float(u0.y << 16),         acc[j][2]);
            acc[j][3] = fmaf(v0, __uint_as_float(u0.y & 0xFFFF0000u), acc[j][3]);
            acc[j][0] = fmaf(v1, __uint_as_float(u1.x << 16),         acc[j][0]);
            acc[j][1] = fmaf(v1, __uint_as_float(u1.x & 0xFFFF0000u), acc[j][1]);
            acc[j][2] = fmaf(v1, __uint_as_float(u1.y << 16),         acc[j][2]);
            acc[j][3] = fmaf(v1, __uint_as_float(u1.y & 0xFFFF0000u), acc[j][3]);
            acc[j][0] = fmaf(v2, __uint_as_float(u2.x << 16),         acc[j][0]);
            acc[j][1] = fmaf(v2, __uint_as_float(u2.x & 0xFFFF0000u), acc[j][1]);
            acc[j][2] = fmaf(v2, __uint_as_float(u2.y << 16),         acc[j][2]);
            acc[j][3] = fmaf(v2, __uint_as_float(u2.y & 0xFFFF0000u), acc[j][3]);
            acc[j][0] = fmaf(v3, __uint_as_float(u3.x << 16),         acc[j][0]);
            acc[j][1] = fmaf(v3, __uint_as_float(u3.x & 0xFFFF0000u), acc[j][1]);
            acc[j][2] = fmaf(v3, __uint_as_float(u3.y << 16),         acc[j][2]);
            acc[j][3] = fmaf(v3, __uint_as_float(u3.y & 0xFFFF0000u), acc[j][3]);
        }
        // tail: halves alternate remaining edges
        for (int i = k + h; i < c; i += 2) {
            int2 e = se[o + i];
            uint2 u = *(const uint2*)(supb + ((e.x & 0x1FFFF) << 7) + fe);
            float v = __int_as_float(e.y);
            acc[j][0] = fmaf(v, __uint_as_float(u.x << 16),         acc[j][0]);
            acc[j][1] = fmaf(v, __uint_as_float(u.x & 0xFFFF0000u), acc[j][1]);
            acc[j][2] = fmaf(v, __uint_as_float(u.y << 16),         acc[j][2]);
            acc[j][3] = fmaf(v, __uint_as_float(u.y & 0xFFFF0000u), acc[j][3]);
        }
    }

    const float4 bv = *((const float4*)bias + l5);
    const int rbase = b << RSHIFT;
#pragma unroll
    for (int j = 0; j < 8; ++j) {
        // combine the two halves' partial sums (same features, disjoint edges)
#pragma unroll
        for (int q = 0; q < 4; ++q) acc[j][q] += __shfl_xor(acc[j][q], 32);
        const int grow = rbase + wave * 8 + j;
        if (((j & 1) == h) && grow < N_NODES) {
            float4 o4;
            o4.x = fmaxf(acc[j][0] + bv.x, 0.f);
            o4.y = fmaxf(acc[j][1] + bv.y, 0.f);
            o4.z = fmaxf(acc[j][2] + bv.z, 0.f);
            o4.w = fmaxf(acc[j][3] + bv.w, 0.f);
            *((float4*)(out + (size_t)grow * OUT_F) + l5) = o4;
        }
    }
}

extern "C" void kernel_launch(void* const* d_in, const int* in_sizes, int n_in,
                              void* d_out, int out_size, void* d_ws, size_t ws_size,
                              hipStream_t stream) {
    const float* x       = (const float*)d_in[0];
    const int*   adj_row = (const int*)d_in[1];
    const int*   adj_col = (const int*)d_in[2];
    const float* adj_val = (const float*)d_in[3];
    const float* weight  = (const float*)d_in[4];
    const float* bias    = (const float*)d_in[5];
    float* out = (float*)d_out;
    const int E = in_sizes[1];

    char* p = (char*)d_ws;
    unsigned short* supb = (unsigned short*)p;  p += (size_t)N_NODES * OUT_F * 2;  // 25.6 MB
    int2* ebuf           = (int2*)p;            p += (size_t)NB * CAPG * 8;        // 32.0 MB
    unsigned short* wT   = (unsigned short*)p;  p += (size_t)OUT_F * IN_F * 2;     // 64 KB
    int* gcur            = (int*)p;             p += (size_t)NB * 4;               // 6.25 KB

    wt_kernel<<<OUT_F, 256, 0, stream>>>(weight, wT, gcur);
    gemm_mfma_kernel<<<N_NODES / 32, 256, 0, stream>>>(x, wT, supb);
    scatter_kernel<<<(E + CHUNK_SC - 1) / CHUNK_SC, 256, 0, stream>>>(adj_row, adj_col,
                                                                      adj_val, gcur, ebuf, E);
    spmm_kernel<<<NB, 512, 0, stream>>>(ebuf, gcur, supb, bias, out);
}

// Round 2
// 371.970 us; speedup vs baseline: 1.0996x; 1.0996x over previous
//
#include <hip/hip_runtime.h>

#define N_NODES 100000
#define IN_F 256
#define OUT_F 128
#define RPB 64                                   // rows per bucket
#define RSHIFT 6
#define NB 1563                                  // ceil(N_NODES/RPB)
#define CAPG 2560                                // fixed per-bucket ebuf capacity
#define CHUNK_SC 4096                            // edges per scatter block

typedef short bf16x8 __attribute__((ext_vector_type(8)));
typedef float f32x4  __attribute__((ext_vector_type(4)));

static __device__ __forceinline__ unsigned short f2bf(float f) {
    unsigned int u = __float_as_uint(f);
    u = (u + 0x7FFF + ((u >> 16) & 1)) >> 16;    // round-to-nearest-even
    return (unsigned short)u;
}

// ---------------- w transpose + bf16 cast + gcur init ----------------------
__global__ __launch_bounds__(256) void wt_kernel(const float* __restrict__ w,
                                                 unsigned short* __restrict__ wT,
                                                 int* __restrict__ gcur) {
    int n = blockIdx.x;                          // 0..127
    int k = threadIdx.x;                         // 0..255
    wT[n * IN_F + k] = f2bf(w[(size_t)k * OUT_F + n]);
    if (blockIdx.x < 7) {
        int i = blockIdx.x * 256 + threadIdx.x;
        if (i < NB) gcur[i] = i * CAPG;
    }
}

// ---------------- MFMA GEMM: B-in-registers, one barrier per block ----------
// Block 256 threads (4 waves). Wave w owns cols w*32..w*32+31 with the full
// K=256 of W held in 64 VGPR of bf16 fragments (loaded once from L2-hot wT).
// A tile (32 rows x 256) staged once -> single __syncthreads -> 32 MFMA/wave.
__global__ __launch_bounds__(256) void gemm_mfma_kernel(const float* __restrict__ x,
                                                        const unsigned short* __restrict__ wT,
                                                        unsigned short* __restrict__ supb) {
    __shared__ unsigned short A_lds[32][264];    // +8 pad, 16B-aligned rows (16.9 KB)

    const int tid  = threadIdx.x;
    const int wave = tid >> 6;                   // 0..3
    const int lane = tid & 63;
    const int quad = lane >> 4;                  // 0..3
    const int l15  = lane & 15;
    const int row_base = blockIdx.x * 32;        // 100000/32 = 3125 exact

    // B fragments: bfrag[ct][ks] covers cols wave*32+ct*16+(0..15), k ks*32+quad*8
    bf16x8 bfrag[2][8];
    {
        const unsigned short* wb = wT + (size_t)(wave * 32 + l15) * IN_F + quad * 8;
#pragma unroll
        for (int ct = 0; ct < 2; ++ct)
#pragma unroll
            for (int ks = 0; ks < 8; ++ks)
                bfrag[ct][ks] = *(const bf16x8*)(wb + ct * 16 * IN_F + ks * 32);
    }

    // stage A: 8192 floats, flat coalesced float4 loads (1 KB/wave-instr)
    {
        const float* xb = x + (size_t)row_base * IN_F;
#pragma unroll
        for (int i = 0; i < 8; ++i) {
            int fidx = i * 1024 + tid * 4;
            float4 a = *(const float4*)(xb + fidx);
            int r = fidx >> 8;
            int c = fidx & 255;
            ushort4 u = {f2bf(a.x), f2bf(a.y), f2bf(a.z), f2bf(a.w)};
            *(ushort4*)&A_lds[r][c] = u;
        }
    }
    __syncthreads();

    f32x4 acc[2][2];
#pragma unroll
    for (int rt = 0; rt < 2; ++rt)
#pragma unroll
        for (int ct = 0; ct < 2; ++ct) acc[rt][ct] = (f32x4){0.f, 0.f, 0.f, 0.f};

#pragma unroll
    for (int ks = 0; ks < 8; ++ks) {
        bf16x8 a0 = *(const bf16x8*)&A_lds[l15][ks * 32 + quad * 8];
        bf16x8 a1 = *(const bf16x8*)&A_lds[16 + l15][ks * 32 + quad * 8];
        acc[0][0] = __builtin_amdgcn_mfma_f32_16x16x32_bf16(a0, bfrag[0][ks], acc[0][0], 0, 0, 0);
        acc[0][1] = __builtin_amdgcn_mfma_f32_16x16x32_bf16(a0, bfrag[1][ks], acc[0][1], 0, 0, 0);
        acc[1][0] = __builtin_amdgcn_mfma_f32_16x16x32_bf16(a1, bfrag[0][ks], acc[1][0], 0, 0, 0);
        acc[1][1] = __builtin_amdgcn_mfma_f32_16x16x32_bf16(a1, bfrag[1][ks], acc[1][1], 0, 0, 0);
    }

    // C/D layout: col = lane&15, row = quad*4 + reg
#pragma unroll
    for (int rt = 0; rt < 2; ++rt)
#pragma unroll
        for (int ct = 0; ct < 2; ++ct)
#pragma unroll
            for (int r = 0; r < 4; ++r) {
                int orow = row_base + rt * 16 + quad * 4 + r;
                int ocol = wave * 32 + ct * 16 + l15;
                supb[(size_t)orow * OUT_F + ocol] = f2bf(acc[rt][ct][r]);
            }
}

// ---------------- scatter: LDS counting-sort + coalesced run writes ---------
// Sort the chunk's edges by bucket in LDS, reserve one contiguous global run
// per bucket, then write positions in sorted order so consecutive lanes hit
// consecutive addresses (sector-merged writes instead of random 8B stores).
__global__ __launch_bounds__(256) void scatter_kernel(const int* __restrict__ adj_row,
                                                      const int* __restrict__ adj_col,
                                                      const float* __restrict__ adj_val,
                                                      int* __restrict__ gcur,
                                                      int2* __restrict__ ebuf, int E) {
    __shared__ int pref[NB + 1];                 // counts -> exclusive prefix -> rank cursor -> ends
    __shared__ int shf[NB];                      // global base - local start, per bucket
    __shared__ int2 se[CHUNK_SC];                // 32 KB sorted edges
    __shared__ int wsum[4];

    const int tid  = threadIdx.x;
    const int base = blockIdx.x * CHUNK_SC;
    const int m    = min(CHUNK_SC, E - base);
    const int nv   = m >> 2;

    for (int b = tid; b <= NB; b += 256) pref[b] = 0;
    __syncthreads();

    // pass 1: histogram (int4 loads)
    for (int j = tid; j < nv; j += 256) {
        int4 r4 = ((const int4*)(adj_row + base))[j];
        atomicAdd(&pref[r4.x >> RSHIFT], 1);
        atomicAdd(&pref[r4.y >> RSHIFT], 1);
        atomicAdd(&pref[r4.z >> RSHIFT], 1);
        atomicAdd(&pref[r4.w >> RSHIFT], 1);
    }
    if (tid < (m & 3)) atomicAdd(&pref[adj_row[base + (nv << 2) + tid] >> RSHIFT], 1);
    __syncthreads();

    // block-wide exclusive prefix scan over pref[0..NB)
    {
        int loc[7];
        const int bb = tid * 7;                  // 256*7 = 1792 >= NB
        int s = 0;
#pragma unroll
        for (int g = 0; g < 7; ++g) {
            int b = bb + g;
            int v = (b < NB) ? pref[b] : 0;
            loc[g] = s;
            s += v;
        }
        const int lane = tid & 63, wv = tid >> 6;
        int inc = s;
        for (int d = 1; d < 64; d <<= 1) {
            int t = __shfl_up(inc, d, 64);
            if (lane >= d) inc += t;
        }
        if (lane == 63) wsum[wv] = inc;
        __syncthreads();                         // counts all read; wsum visible
        int wb2 = 0;
        for (int k = 0; k < wv; ++k) wb2 += wsum[k];
        const int texcl = wb2 + inc - s;         // exclusive prefix of this thread
#pragma unroll
        for (int g = 0; g < 7; ++g) {
            int b = bb + g;
            if (b < NB) pref[b] = texcl + loc[g];
        }
        if (tid == 255) pref[NB] = texcl + s;    // total
    }
    __syncthreads();

    // reserve one contiguous global run per non-empty bucket
    for (int b = tid; b < NB; b += 256) {
        int s0 = pref[b];
        int c  = pref[b + 1] - s0;
        if (c > 0) shf[b] = atomicAdd(&gcur[b], c) - s0;
    }
    __syncthreads();

    // pass 2: rank + sort into LDS (pref[b] marches start -> end)
    for (int j = tid; j < nv; j += 256) {
        int4   c4 = ((const int4*)(adj_col + base))[j];
        int4   r4 = ((const int4*)(adj_row + base))[j];
        float4 v4 = ((const float4*)(adj_val + base))[j];
        int p;
        p = atomicAdd(&pref[r4.x >> RSHIFT], 1);
        se[p] = make_int2(c4.x | ((r4.x & (RPB - 1)) << 17), __float_as_int(v4.x));
        p = atomicAdd(&pref[r4.y >> RSHIFT], 1);
        se[p] = make_int2(c4.y | ((r4.y & (RPB - 1)) << 17), __float_as_int(v4.y));
        p = atomicAdd(&pref[r4.z >> RSHIFT], 1);
        se[p] = make_int2(c4.z | ((r4.z & (RPB - 1)) << 17), __float_as_int(v4.z));
        p = atomicAdd(&pref[r4.w >> RSHIFT], 1);
        se[p] = make_int2(c4.w | ((r4.w & (RPB - 1)) << 17), __float_as_int(v4.w));
    }
    if (tid < (m & 3)) {
        int i = base + (nv << 2) + tid;
        int r = adj_row[i];
        int p = atomicAdd(&pref[r >> RSHIFT], 1);
        se[p] = make_int2(adj_col[i] | ((r & (RPB - 1)) << 17), __float_as_int(adj_val[i]));
    }
    __syncthreads();

    // write-out in sorted order: consecutive p -> consecutive global addresses
    // post-pass2 pref[b] == end offset of bucket b (monotone) -> binary search
    for (int p = tid; p < m; p += 256) {
        int lo = 0, hi = NB - 1;
        while (lo < hi) {
            int mid = (lo + hi) >> 1;
            if (pref[mid] > p) hi = mid; else lo = mid + 1;
        }
        int g = shf[lo] + p;
        if (g < (lo + 1) * CAPG) ebuf[g] = se[p];  // overflow guard
    }
}

// ---------------- SpMM: single-chunk LDS counting-sort + register acc -------
__global__ __launch_bounds__(512) void spmm_kernel(const int2* __restrict__ ebuf,
                                                   const int* __restrict__ gcur,
                                                   const unsigned short* __restrict__ supb,
                                                   const float* __restrict__ bias,
                                                   float* __restrict__ out) {
    __shared__ int2 se[CAPG];                    // 20 KB sorted edges
    __shared__ int cnt[RPB];
    __shared__ int off[RPB];
    __shared__ int cur[RPB];

    const int tid  = threadIdx.x;
    const int b    = blockIdx.x;
    const int wave = tid >> 6;
    const int lane = tid & 63;
    const int f0   = lane * 2;

    const int start = b * CAPG;
    int m = gcur[b] - start;
    if (m > CAPG) m = CAPG;

    if (tid < RPB) cnt[tid] = 0;
    __syncthreads();

    int2 ev[5];
#pragma unroll
    for (int j = 0; j < 5; ++j) {
        int i = j * 512 + tid;
        if (i < m) {
            ev[j] = ebuf[start + i];
            atomicAdd(&cnt[ev[j].x >> 17], 1);
        }
    }
    __syncthreads();

    if (tid < RPB) {
        int v = cnt[tid];
        int s = v;
#pragma unroll
        for (int d = 1; d < RPB; d <<= 1) {
            int t = __shfl_up(s, d, 64);
            if (tid >= d) s += t;
        }
        off[tid] = s - v;
        cur[tid] = s - v;
    }
    __syncthreads();

#pragma unroll
    for (int j = 0; j < 5; ++j) {
        int i = j * 512 + tid;
        if (i < m) {
            int p = atomicAdd(&cur[ev[j].x >> 17], 1);
            se[p] = ev[j];
        }
    }
    __syncthreads();

    float2 acc[8];
#pragma unroll
    for (int j = 0; j < 8; ++j) acc[j] = make_float2(0.f, 0.f);

#pragma unroll
    for (int j = 0; j < 8; ++j) {
        int r = wave * 8 + j;
        int o = off[r];
        int c = cnt[r];
        float2 a = acc[j];
        int i = 0;
        for (; i + 4 <= c; i += 4) {
            int2 e0 = se[o + i + 0];
            int2 e1 = se[o + i + 1];
            int2 e2 = se[o + i + 2];
            int2 e3 = se[o + i + 3];
            unsigned int u0 = *(const unsigned int*)(supb + (size_t)(e0.x & 0x1FFFF) * OUT_F + f0);
            unsigned int u1 = *(const unsigned int*)(supb + (size_t)(e1.x & 0x1FFFF) * OUT_F + f0);
            unsigned int u2 = *(const unsigned int*)(supb + (size_t)(e2.x & 0x1FFFF) * OUT_F + f0);
            unsigned int u3 = *(const unsigned int*)(supb + (size_t)(e3.x & 0x1FFFF) * OUT_F + f0);
            float v0 = __int_as_float(e0.y), v1 = __int_as_float(e1.y);
            float v2 = __int_as_float(e2.y), v3 = __int_as_float(e3.y);
            a.x += v0 * __uint_as_float(u0 << 16);
            a.y += v0 * __uint_as_float(u0 & 0xFFFF0000u);
            a.x += v1 * __uint_as_float(u1 << 16);
            a.y += v1 * __uint_as_float(u1 & 0xFFFF0000u);
            a.x += v2 * __uint_as_float(u2 << 16);
            a.y += v2 * __uint_as_float(u2 & 0xFFFF0000u);
            a.x += v3 * __uint_as_float(u3 << 16);
            a.y += v3 * __uint_as_float(u3 & 0xFFFF0000u);
        }
        for (; i < c; ++i) {
            int2 e = se[o + i];
            unsigned int u = *(const unsigned int*)(supb + (size_t)(e.x & 0x1FFFF) * OUT_F + f0);
            float v = __int_as_float(e.y);
            a.x += v * __uint_as_float(u << 16);
            a.y += v * __uint_as_float(u & 0xFFFF0000u);
        }
        acc[j] = a;
    }

    float2 bv = *((const float2*)bias + lane);
    const int rbase = b << RSHIFT;
#pragma unroll
    for (int j = 0; j < 8; ++j) {
        int grow = rbase + wave * 8 + j;
        if (grow < N_NODES) {
            float2 o;
            o.x = fmaxf(acc[j].x + bv.x, 0.f);
            o.y = fmaxf(acc[j].y + bv.y, 0.f);
            *((float2*)(out + (size_t)grow * OUT_F) + lane) = o;
        }
    }
}

extern "C" void kernel_launch(void* const* d_in, const int* in_sizes, int n_in,
                              void* d_out, int out_size, void* d_ws, size_t ws_size,
                              hipStream_t stream) {
    const float* x       = (const float*)d_in[0];
    const int*   adj_row = (const int*)d_in[1];
    const int*   adj_col = (const int*)d_in[2];
    const float* adj_val = (const float*)d_in[3];
    const float* weight  = (const float*)d_in[4];
    const float* bias    = (const float*)d_in[5];
    float* out = (float*)d_out;
    const int E = in_sizes[1];

    char* p = (char*)d_ws;
    unsigned short* supb = (unsigned short*)p;  p += (size_t)N_NODES * OUT_F * 2;  // 25.6 MB
    int2* ebuf           = (int2*)p;            p += (size_t)NB * CAPG * 8;        // 32.0 MB
    unsigned short* wT   = (unsigned short*)p;  p += (size_t)OUT_F * IN_F * 2;     // 64 KB
    int* gcur            = (int*)p;             p += (size_t)NB * 4;               // 6.25 KB

    wt_kernel<<<OUT_F, 256, 0, stream>>>(weight, wT, gcur);
    gemm_mfma_kernel<<<N_NODES / 32, 256, 0, stream>>>(x, wT, supb);
    scatter_kernel<<<(E + CHUNK_SC - 1) / CHUNK_SC, 256, 0, stream>>>(adj_row, adj_col,
                                                                      adj_val, gcur, ebuf, E);
    spmm_kernel<<<NB, 512, 0, stream>>>(ebuf, gcur, supb, bias, out);
}